// Round 4
// baseline (31743.350 us; speedup 1.0000x reference)
//
#include <hip/hip_runtime.h>

#define T_SEQ 8192
#define POISON 0xAAAAAAAAu

typedef float vfloat4 __attribute__((ext_vector_type(4)));

static __device__ __forceinline__ float sigm(float x)  { return 1.0f / (1.0f + __expf(-x)); }
static __device__ __forceinline__ float tanhq(float x) { return 1.0f - 2.0f / (__expf(2.0f * x) + 1.0f); }

// Relaxed agent-scope atomics -> sc-bypassing global ops served by the
// device-coherent L3. No fences in the step loop: the polled word IS the
// data (harness 0xAA poison = not-yet-written sentinel).
static __device__ __forceinline__ void astore(unsigned* p, float v) {
  __hip_atomic_store(p, __float_as_uint(v), __ATOMIC_RELAXED, __HIP_MEMORY_SCOPE_AGENT);
}
// One-instruction 16B poll load, bypassing L1/L2 (sc0 sc1) so repeated polls
// observe other XCDs' stores. 4 words checked per line-request (dedupe).
static __device__ __forceinline__ vfloat4 pollLoad4(const float* p) {
  vfloat4 v;
  asm volatile("global_load_dwordx4 %0, %1, off sc0 sc1\n\ts_waitcnt vmcnt(0)"
               : "=v"(v) : "v"(p) : "memory");
  return v;
}
static __device__ __forceinline__ bool valid4(vfloat4 v) {
  return (__float_as_uint(v[0]) != POISON) && (__float_as_uint(v[1]) != POISON) &&
         (__float_as_uint(v[2]) != POISON) && (__float_as_uint(v[3]) != POISON);
}

// LDS pad-swizzle: logical word i -> physical i + (i>>6)*4. K-chunk q (64 fl)
// starts at physical 68q (16B aligned); float4 reads are conflict-free (L0)
// or 2-way (free) for L1. Proven R3: SQ_LDS_BANK_CONFLICT = 0.
#define SWZ(i) ((i) + (((i) >> 6) << 2))

// 16 named float4 weight locals (64 floats/thread), macro-unrolled + asm-pinned
// (R2 lesson: unpinned locals were rematerialized from global every step).
#define WLIST(X) X(0) X(1) X(2) X(3) X(4) X(5) X(6) X(7) X(8) X(9) X(10) X(11) X(12) X(13) X(14) X(15)
#define DECLW(k) float4 W##k = wp4[k];
#define PINW(k)  asm volatile("" : "+v"(W##k.x), "+v"(W##k.y), "+v"(W##k.z), "+v"(W##k.w));
#define DOFMA(k) { float4 hv = hp4[k]; \
  a0 = __builtin_fmaf(W##k.x, hv.x, a0); a1 = __builtin_fmaf(W##k.y, hv.y, a1); \
  a2 = __builtin_fmaf(W##k.z, hv.z, a2); a3 = __builtin_fmaf(W##k.w, hv.w, a3); }

// blocks 0..31  : layer 0. 512 thr: 64 gate-rows (16 h x 4 g), 8 thr/row (K=512)
// blocks 32..95 : layer 1. 512 thr: 32 gate-rows ( 8 h x 4 g), 16 thr/row (K=1024)
__global__ __launch_bounds__(512, 1) void lstm_main(
    const float* __restrict__ input_seq,
    const float* __restrict__ w_ih0, const float* __restrict__ w_hh0,
    const float* __restrict__ b_ih0, const float* __restrict__ b_hh0,
    const float* __restrict__ w_ih1, const float* __restrict__ w_hh1,
    const float* __restrict__ b_ih1, const float* __restrict__ b_hh1,
    float* __restrict__ h0buf, float* __restrict__ h1buf)
{
  __shared__ float xin[T_SEQ];                   // 32 KB (layer-0 blocks only)
  __shared__ __align__(16) float hb[2][1088];    // double-buffered, swizzled h rows
  const int tid  = threadIdx.x;
  const int lane = tid & 63;
  const int wv   = tid >> 6;                     // 0..7
  const int wg   = blockIdx.x;
  int gd = 1 << 22;                              // poll budget: break (wrong) not hang

  if (wg < 32) {
    // ================= layer 0 =================
    for (int i = tid; i < T_SEQ; i += 512) xin[i] = input_seq[i];
    const int q  = tid & 7;                      // K-chunk (64 floats)
    const int lr = tid >> 3;                     // gate-row 0..63
    const int jl = lr >> 2;                      // local h 0..15
    const int g  = lr & 3;                       // gate (i,f,g,o)
    const int grow = g * 512 + wg * 16 + jl;
    const float4* wp4 = (const float4*)(w_hh0 + (size_t)grow * 512 + q * 64);
    WLIST(DECLW)
    WLIST(PINW)
    const float wx   = w_ih0[grow];
    const float bias = b_ih0[grow] + b_hh0[grow];
    const int houtIdx = wg * 16 + 2 * wv + (lane >> 5);  // lanes 0 and 32 publish
    float c = 0.0f;
    __syncthreads();                             // xin ready

    for (int t = 0; t < T_SEQ; ++t) {
      float* hl = hb[t & 1];
      if (tid < 128) {                           // 2 waves stage; rest sleep at barrier
        vfloat4 v;
        if (t == 0) {
          v[0] = v[1] = v[2] = v[3] = 0.0f;
        } else {
          const float* src = h0buf + (size_t)(t - 1) * 512 + 4 * tid;
          for (;;) {
            v = pollLoad4(src);
            if (valid4(v)) break;
            if (--gd <= 0) break;
            __builtin_amdgcn_s_sleep(1);
          }
        }
        *(vfloat4*)&hl[SWZ(4 * tid)] = v;
      }
      __syncthreads();
      const float4* hp4 = (const float4*)hl + q * 17;    // 68-float chunk stride
      float a0 = 0.f, a1 = 0.f, a2 = 0.f, a3 = 0.f;
      WLIST(DOFMA)
      float acc = (a0 + a1) + (a2 + a3);
      acc += __shfl_xor(acc, 1);                 // reduce over 8 K-chunks
      acc += __shfl_xor(acc, 2);
      acc += __shfl_xor(acc, 4);
      float pre = acc + bias + wx * xin[t];
      float pf = __shfl_xor(pre, 8);             // gather f,g,o pre-acts
      float pg = __shfl_xor(pre, 16);
      float po = __shfl_xor(pre, 24);
      float i_ = sigm(pre), f_ = sigm(pf), g_ = tanhq(pg), o_ = sigm(po);
      c = f_ * c + i_ * g_;
      float h = o_ * tanhq(c);
      if ((lane & 31) == 0)
        astore((unsigned*)(h0buf + (size_t)t * 512 + houtIdx), h);
    }
  } else {
    // ================= layer 1 =================
    const int wg1 = wg - 32;                     // 0..63
    const int q  = tid & 15;                     // 0..7 -> w_ih1/h0, 8..15 -> w_hh1/h1
    const int lr = tid >> 4;                     // 0..31
    const int jl = lr >> 2;                      // 0..7 (== wv)
    const int g  = lr & 3;
    const int grow = g * 512 + wg1 * 8 + jl;
    const float* wsrc = (q < 8) ? (w_ih1 + (size_t)grow * 512 + q * 64)
                                : (w_hh1 + (size_t)grow * 512 + (q - 8) * 64);
    const float4* wp4 = (const float4*)wsrc;
    WLIST(DECLW)
    WLIST(PINW)
    const float bias = b_ih1[grow] + b_hh1[grow];
    const int houtIdx = wg1 * 8 + wv;            // lane 0 of each wave publishes
    float c = 0.0f;
    __syncthreads();

    for (int t = 0; t < T_SEQ; ++t) {
      float* hl = hb[t & 1];
      if (tid < 256) {                           // 4 waves stage; rest sleep at barrier
        vfloat4 v;
        if (tid < 128) {                         // h0[t] (always polled)
          const float* src = h0buf + (size_t)t * 512 + 4 * tid;
          for (;;) {
            v = pollLoad4(src);
            if (valid4(v)) break;
            if (--gd <= 0) break;
            __builtin_amdgcn_s_sleep(1);
          }
          *(vfloat4*)&hl[SWZ(4 * tid)] = v;
        } else {                                 // h1[t-1] (zeros at t==0)
          const int p2 = tid - 128;
          if (t == 0) {
            v[0] = v[1] = v[2] = v[3] = 0.0f;
          } else {
            const float* src = h1buf + (size_t)(t - 1) * 512 + 4 * p2;
            for (;;) {
              v = pollLoad4(src);
              if (valid4(v)) break;
              if (--gd <= 0) break;
              __builtin_amdgcn_s_sleep(1);
            }
          }
          *(vfloat4*)&hl[544 + SWZ(4 * p2)] = v;
        }
      }
      __syncthreads();
      const float4* hp4 = (const float4*)hl + q * 17;    // q>=8 lands in h1 half
      float a0 = 0.f, a1 = 0.f, a2 = 0.f, a3 = 0.f;
      WLIST(DOFMA)
      float acc = (a0 + a1) + (a2 + a3);
      acc += __shfl_xor(acc, 1);                 // reduce over 16 K-chunks
      acc += __shfl_xor(acc, 2);
      acc += __shfl_xor(acc, 4);
      acc += __shfl_xor(acc, 8);
      float pre = acc + bias;
      float pf = __shfl_xor(pre, 16);
      float pg = __shfl_xor(pre, 32);
      float po = __shfl_xor(pre, 48);
      float i_ = sigm(pre), f_ = sigm(pf), g_ = tanhq(pg), o_ = sigm(po);
      c = f_ * c + i_ * g_;
      float h = o_ * tanhq(c);
      if (lane == 0)
        astore((unsigned*)(h1buf + (size_t)t * 512 + houtIdx), h);
    }
  }
}

// ---------------- MLP head on the final hidden state ----------------
__global__ void lstm_head(const float* __restrict__ h1buf,
                          const float* __restrict__ w1, const float* __restrict__ b1,
                          const float* __restrict__ w2, const float* __restrict__ b2,
                          float* __restrict__ out)
{
  const int lane = threadIdx.x;     // 64 threads
  const float* h2 = h1buf + (size_t)(T_SEQ - 1) * 512;
  float hv[8];
  #pragma unroll
  for (int k = 0; k < 8; ++k) hv[k] = h2[lane * 8 + k];
  float o = 0.0f;
  for (int r = 0; r < 20; ++r) {
    const float* wr = w1 + r * 512 + lane * 8;
    float p = 0.0f;
    #pragma unroll
    for (int k = 0; k < 8; ++k) p += wr[k] * hv[k];
    #pragma unroll
    for (int m = 1; m < 64; m <<= 1) p += __shfl_xor(p, m);
    o += w2[r] * (p + b1[r]);
  }
  if (lane == 0) out[0] = o + b2[0];
}

extern "C" void kernel_launch(void* const* d_in, const int* in_sizes, int n_in,
                              void* d_out, int out_size, void* d_ws, size_t ws_size,
                              hipStream_t stream)
{
  const float* input_seq = (const float*)d_in[0];
  const float* w_ih0 = (const float*)d_in[1];
  const float* w_hh0 = (const float*)d_in[2];
  const float* b_ih0 = (const float*)d_in[3];
  const float* b_hh0 = (const float*)d_in[4];
  const float* w_ih1 = (const float*)d_in[5];
  const float* w_hh1 = (const float*)d_in[6];
  const float* b_ih1 = (const float*)d_in[7];
  const float* b_hh1 = (const float*)d_in[8];
  const float* w1 = (const float*)d_in[9];
  const float* b1 = (const float*)d_in[10];
  const float* w2 = (const float*)d_in[11];
  const float* b2 = (const float*)d_in[12];
  (void)in_sizes; (void)n_in; (void)out_size; (void)ws_size;

  char* ws = (char*)d_ws;
  float* h0buf = (float*)(ws);                                  // [T][512]
  float* h1buf = (float*)(ws + (size_t)T_SEQ * 512 * 4);        // [T][512]

  hipLaunchKernelGGL(lstm_main, dim3(96), dim3(512), 0, stream,
                     input_seq, w_ih0, w_hh0, b_ih0, b_hh0,
                     w_ih1, w_hh1, b_ih1, b_hh1, h0buf, h1buf);
  hipLaunchKernelGGL(lstm_head, dim3(1), dim3(64), 0, stream,
                     h1buf, w1, b1, w2, b2, (float*)d_out);
}

// Round 5
// 24462.384 us; speedup vs baseline: 1.2976x; 1.2976x over previous
//
#include <hip/hip_runtime.h>

#define T_SEQ 8192
#define POISON 0xAAAAAAAAu

typedef float vfloat4 __attribute__((ext_vector_type(4)));

static __device__ __forceinline__ float sigm(float x)  { return 1.0f / (1.0f + __expf(-x)); }
static __device__ __forceinline__ float tanhq(float x) { return 1.0f - 2.0f / (__expf(2.0f * x) + 1.0f); }

// Agent(device)-scope relaxed store: global_store_dword sc1 -> write-through to
// the device-coherent L3. No fences in the step loop: the polled word IS the
// data (harness 0xAA ws-poison = not-yet-written sentinel).
static __device__ __forceinline__ void astore(unsigned* p, float v) {
  __hip_atomic_store(p, __float_as_uint(v), __ATOMIC_RELAXED, __HIP_MEMORY_SCOPE_AGENT);
}
// Agent-scope 16B poll load. sc1 ONLY = device scope (bypass L1/L2, served by
// L3). R4 lesson: sc0+sc1 = SYSTEM scope -> traffic past L3 to HBM
// (FETCH_SIZE +156MB, slower). 4 words validated per line-request (dedupe).
static __device__ __forceinline__ vfloat4 pollLoad4(const float* p) {
  vfloat4 v;
  asm volatile("global_load_dwordx4 %0, %1, off sc1\n\ts_waitcnt vmcnt(0)"
               : "=v"(v) : "v"(p) : "memory");
  return v;
}
static __device__ __forceinline__ bool valid4(vfloat4 v) {
  return (__float_as_uint(v[0]) != POISON) && (__float_as_uint(v[1]) != POISON) &&
         (__float_as_uint(v[2]) != POISON) && (__float_as_uint(v[3]) != POISON);
}

// LDS pad-swizzle: logical word i -> physical i + (i>>6)*4. K-chunk q (64 fl)
// starts at physical 68q (16B aligned); float4 reads conflict-free (proven R3:
// SQ_LDS_BANK_CONFLICT = 0).
#define SWZ(i) ((i) + (((i) >> 6) << 2))

// 16 named float4 weight locals (64 floats/thread). R2: unpinned locals were
// rematerialized from global every step (VGPR=52). R4: a ONE-SHOT pin also
// failed (VGPR=56). Fix: pin INSIDE the step loop -> "+v" each iteration makes
// the weights loop-carried register values that cannot be rematerialized.
#define WLIST(X) X(0) X(1) X(2) X(3) X(4) X(5) X(6) X(7) X(8) X(9) X(10) X(11) X(12) X(13) X(14) X(15)
#define DECLW(k) float4 W##k = wp4[k];
#define PINW(k)  asm volatile("" : "+v"(W##k.x), "+v"(W##k.y), "+v"(W##k.z), "+v"(W##k.w));
#define DOFMA(k) { float4 hv = hp4[k]; \
  a0 = __builtin_fmaf(W##k.x, hv.x, a0); a1 = __builtin_fmaf(W##k.y, hv.y, a1); \
  a2 = __builtin_fmaf(W##k.z, hv.z, a2); a3 = __builtin_fmaf(W##k.w, hv.w, a3); }

// blocks 0..63   : layer 0. 32 gate-rows/block (8 h x 4 g), 8 thr/row (K=512)
// blocks 64..191 : layer 1. 16 gate-rows/block (4 h x 4 g), 16 thr/row (K=1024)
__global__ __launch_bounds__(256, 1) void lstm_main(
    const float* __restrict__ input_seq,
    const float* __restrict__ w_ih0, const float* __restrict__ w_hh0,
    const float* __restrict__ b_ih0, const float* __restrict__ b_hh0,
    const float* __restrict__ w_ih1, const float* __restrict__ w_hh1,
    const float* __restrict__ b_ih1, const float* __restrict__ b_hh1,
    float* __restrict__ h0buf, float* __restrict__ h1buf)
{
  __shared__ float xin[T_SEQ];                   // 32 KB (layer-0 blocks only)
  __shared__ __align__(16) float hb[2][1088];    // double-buffered, swizzled h rows
  const int tid  = threadIdx.x;
  const int lane = tid & 63;
  const int wv   = tid >> 6;                     // 0..3
  const int wg   = blockIdx.x;
  int gd = 1 << 22;                              // poll budget: break (wrong) not hang

  if (wg < 64) {
    // ================= layer 0 =================
    for (int i = tid; i < T_SEQ; i += 256) xin[i] = input_seq[i];
    const int q  = tid & 7;                      // K-chunk (64 floats)
    const int lr = tid >> 3;                     // gate-row 0..31
    const int jl = lr >> 2;                      // local h 0..7
    const int g  = lr & 3;                       // gate (i,f,g,o)
    const int grow = g * 512 + wg * 8 + jl;
    const float4* wp4 = (const float4*)(w_hh0 + (size_t)grow * 512 + q * 64);
    WLIST(DECLW)
    const float wx   = w_ih0[grow];
    const float bias = b_ih0[grow] + b_hh0[grow];
    const int houtIdx = wg * 8 + 2 * wv + (lane >> 5);   // lanes 0 and 32 publish
    float c = 0.0f;
    __syncthreads();                             // xin ready

    for (int t = 0; t < T_SEQ; ++t) {
      WLIST(PINW)                                // loop-carried: no weight remat
      float* hl = hb[t & 1];
      if (tid < 128) {                           // 2 waves stage the 512-fl row
        vfloat4 v;
        if (t == 0) {
          v[0] = v[1] = v[2] = v[3] = 0.0f;
        } else {
          const float* src = h0buf + (size_t)(t - 1) * 512 + 4 * tid;
          for (;;) {
            v = pollLoad4(src);
            if (valid4(v)) break;
            if (--gd <= 0) break;
            __builtin_amdgcn_s_sleep(1);         // backoff: cut spin power
          }
        }
        *(vfloat4*)&hl[SWZ(4 * tid)] = v;
      }
      __syncthreads();
      const float4* hp4 = (const float4*)hl + q * 17;    // 68-float chunk stride
      float a0 = 0.f, a1 = 0.f, a2 = 0.f, a3 = 0.f;
      WLIST(DOFMA)
      float acc = (a0 + a1) + (a2 + a3);
      acc += __shfl_xor(acc, 1);                 // reduce over 8 K-chunks
      acc += __shfl_xor(acc, 2);
      acc += __shfl_xor(acc, 4);
      float pre = acc + bias + wx * xin[t];
      float pf = __shfl_xor(pre, 8);             // gather f,g,o pre-acts
      float pg = __shfl_xor(pre, 16);
      float po = __shfl_xor(pre, 24);
      float i_ = sigm(pre), f_ = sigm(pf), g_ = tanhq(pg), o_ = sigm(po);
      c = f_ * c + i_ * g_;
      float h = o_ * tanhq(c);
      if ((tid & 31) == 0)
        astore((unsigned*)(h0buf + (size_t)t * 512 + houtIdx), h);
    }
  } else {
    // ================= layer 1 =================
    const int wg1 = wg - 64;                     // 0..127
    const int q  = tid & 15;                     // 0..7 -> w_ih1/h0, 8..15 -> w_hh1/h1
    const int lr = tid >> 4;                     // 0..15
    const int jl = lr >> 2;                      // 0..3
    const int g  = lr & 3;
    const int grow = g * 512 + wg1 * 4 + jl;
    const float* wsrc = (q < 8) ? (w_ih1 + (size_t)grow * 512 + q * 64)
                                : (w_hh1 + (size_t)grow * 512 + (q - 8) * 64);
    const float4* wp4 = (const float4*)wsrc;
    WLIST(DECLW)
    const float bias = b_ih1[grow] + b_hh1[grow];
    const int houtIdx = wg1 * 4 + wv;            // lane 0 of each wave publishes
    float c = 0.0f;
    __syncthreads();

    for (int t = 0; t < T_SEQ; ++t) {
      WLIST(PINW)                                // loop-carried: no weight remat
      float* hl = hb[t & 1];
      vfloat4 v;
      if (tid < 128) {                           // h0[t] (always polled)
        const float* src = h0buf + (size_t)t * 512 + 4 * tid;
        for (;;) {
          v = pollLoad4(src);
          if (valid4(v)) break;
          if (--gd <= 0) break;
          __builtin_amdgcn_s_sleep(1);
        }
        *(vfloat4*)&hl[SWZ(4 * tid)] = v;
      } else {                                   // h1[t-1] (zeros at t==0)
        const int p2 = tid - 128;
        if (t == 0) {
          v[0] = v[1] = v[2] = v[3] = 0.0f;
        } else {
          const float* src = h1buf + (size_t)(t - 1) * 512 + 4 * p2;
          for (;;) {
            v = pollLoad4(src);
            if (valid4(v)) break;
            if (--gd <= 0) break;
            __builtin_amdgcn_s_sleep(1);
          }
        }
        *(vfloat4*)&hl[544 + SWZ(4 * p2)] = v;   // 544 = SWZ(512)
      }
      __syncthreads();
      const float4* hp4 = (const float4*)hl + q * 17;    // q>=8 lands in h1 half
      float a0 = 0.f, a1 = 0.f, a2 = 0.f, a3 = 0.f;
      WLIST(DOFMA)
      float acc = (a0 + a1) + (a2 + a3);
      acc += __shfl_xor(acc, 1);                 // reduce over 16 K-chunks
      acc += __shfl_xor(acc, 2);
      acc += __shfl_xor(acc, 4);
      acc += __shfl_xor(acc, 8);
      float pre = acc + bias;
      float pf = __shfl_xor(pre, 16);
      float pg = __shfl_xor(pre, 32);
      float po = __shfl_xor(pre, 48);
      float i_ = sigm(pre), f_ = sigm(pf), g_ = tanhq(pg), o_ = sigm(po);
      c = f_ * c + i_ * g_;
      float h = o_ * tanhq(c);
      if (lane == 0)
        astore((unsigned*)(h1buf + (size_t)t * 512 + houtIdx), h);
    }
  }
}

// ---------------- MLP head on the final hidden state ----------------
__global__ void lstm_head(const float* __restrict__ h1buf,
                          const float* __restrict__ w1, const float* __restrict__ b1,
                          const float* __restrict__ w2, const float* __restrict__ b2,
                          float* __restrict__ out)
{
  const int lane = threadIdx.x;     // 64 threads
  const float* h2 = h1buf + (size_t)(T_SEQ - 1) * 512;
  float hv[8];
  #pragma unroll
  for (int k = 0; k < 8; ++k) hv[k] = h2[lane * 8 + k];
  float o = 0.0f;
  for (int r = 0; r < 20; ++r) {
    const float* wr = w1 + r * 512 + lane * 8;
    float p = 0.0f;
    #pragma unroll
    for (int k = 0; k < 8; ++k) p += wr[k] * hv[k];
    #pragma unroll
    for (int m = 1; m < 64; m <<= 1) p += __shfl_xor(p, m);
    o += w2[r] * (p + b1[r]);
  }
  if (lane == 0) out[0] = o + b2[0];
}

extern "C" void kernel_launch(void* const* d_in, const int* in_sizes, int n_in,
                              void* d_out, int out_size, void* d_ws, size_t ws_size,
                              hipStream_t stream)
{
  const float* input_seq = (const float*)d_in[0];
  const float* w_ih0 = (const float*)d_in[1];
  const float* w_hh0 = (const float*)d_in[2];
  const float* b_ih0 = (const float*)d_in[3];
  const float* b_hh0 = (const float*)d_in[4];
  const float* w_ih1 = (const float*)d_in[5];
  const float* w_hh1 = (const float*)d_in[6];
  const float* b_ih1 = (const float*)d_in[7];
  const float* b_hh1 = (const float*)d_in[8];
  const float* w1 = (const float*)d_in[9];
  const float* b1 = (const float*)d_in[10];
  const float* w2 = (const float*)d_in[11];
  const float* b2 = (const float*)d_in[12];
  (void)in_sizes; (void)n_in; (void)out_size; (void)ws_size;

  char* ws = (char*)d_ws;
  float* h0buf = (float*)(ws);                                  // [T][512]
  float* h1buf = (float*)(ws + (size_t)T_SEQ * 512 * 4);        // [T][512]

  hipLaunchKernelGGL(lstm_main, dim3(192), dim3(256), 0, stream,
                     input_seq, w_ih0, w_hh0, b_ih0, b_hh0,
                     w_ih1, w_hh1, b_ih1, b_hh1, h0buf, h1buf);
  hipLaunchKernelGGL(lstm_head, dim3(1), dim3(64), 0, stream,
                     h1buf, w1, b1, w2, b2, (float*)d_out);
}